// Round 10
// baseline (8973.241 us; speedup 1.0000x reference)
//
#include <hip/hip_runtime.h>

typedef short bf16x8 __attribute__((ext_vector_type(8)));
typedef float f32x4 __attribute__((ext_vector_type(4)));
typedef unsigned short u16;
typedef unsigned int u32;
typedef unsigned long long u64;

static constexpr int B = 2048, S = 128, D = 128, H = 256;
static constexpr size_t PH = (size_t)B * H;

// LDS (u16 units): WRES up to 8 pair-tiles x [128 zr][64 k] = 65536 (128KB)
//                  WP  [16 rows][32 slots][8]               = 4096  (8KB)
#define L_WP   65536
#define L_TOT  69632     // 139264 bytes

__device__ __forceinline__ u16 f2bf(float x){ u32 u=__float_as_uint(x); return (u16)((u + 0x7fffu + ((u>>16)&1u))>>16); }
__device__ __forceinline__ float bf2f(u16 h){ return __uint_as_float(((u32)h)<<16); }
__device__ __forceinline__ float fsig(float x){ return 1.0f/(1.0f+__expf(-x)); }
__device__ __forceinline__ float ftanh(float x){ return 1.0f - 2.0f/(__expf(2.0f*x)+1.0f); }

__device__ __forceinline__ void gl_lds16(const void* g, const u16* l){
  __builtin_amdgcn_global_load_lds((const __attribute__((address_space(1))) void*)g,
      (__attribute__((address_space(3))) void*)l, 16, 0, 0);
}
__device__ __forceinline__ u64 ald64(const u32* p){
  return __hip_atomic_load((const u64*)p, __ATOMIC_RELAXED, __HIP_MEMORY_SCOPE_AGENT);
}
__device__ __forceinline__ u32 ald32(const u32* p){
  return __hip_atomic_load(p, __ATOMIC_RELAXED, __HIP_MEMORY_SCOPE_AGENT);
}
__device__ __forceinline__ void ast32(u32* p, u32 v){
  __hip_atomic_store(p, v, __ATOMIC_RELAXED, __HIP_MEMORY_SCOPE_AGENT);
}

__global__ __launch_bounds__(256) void cvtk(const float* __restrict__ s, u16* __restrict__ d, int n){
  int i = (blockIdx.x*256 + threadIdx.x)*4;
  if (i+3 < n){
    float4 v = *(const float4*)(s+i);
    d[i]=f2bf(v.x); d[i+1]=f2bf(v.y); d[i+2]=f2bf(v.z); d[i+3]=f2bf(v.w);
  }
}
__global__ __launch_bounds__(256) void addk(const float* __restrict__ a, const float* __restrict__ b,
                                            float* __restrict__ o, int n){
  int i = blockIdx.x*256 + threadIdx.x; if (i<n) o[i]=a[i]+b[i];
}

struct Ph {
  const float* xf; int t;          // fp32 x source for tiles < N1 (enc L0) or null
  const u32 *A1, *A2;              // packed hi|lo u32 planes
  size_t gb;                       // batch-row base (block covers 64*MF rows)
  const float* bs;                 // fused bias (4H fp32)
  u32* outP;                       // h output plane (packed hi|lo)
  int doprj; const float* bout; float* out; int tau;
};

// Resident W: pair-tiles [128 zr][64 k]; slot s holds k-octet o = s ^ (zr&7)
// (o>>2 selects K32 tile within pair, o&3 octet within tile). Linear LDS dest,
// swizzle applied on the global source address.
__device__ __forceinline__ void stage_res(u16* lds, int nn, int tid,
    const u16* W1, int ldw1, int t1, const u16* W2, int ldw2, int t2){
  const int np = (t1 + t2) >> 1;
  for (int pp = 0; pp < np; ++pp){
    #pragma unroll
    for (int p2 = 0; p2 < 2; ++p2){
      const int idx = p2*512 + tid;
      const int zr = idx >> 3, sl = idx & 7;
      const int o = sl ^ (zr & 7);
      const int kt = pp*2 + (o >> 2);
      const size_t zrow = (size_t)((zr >> 5) * H + nn*32 + (zr & 31));
      const u16* src = (kt < t1) ? (W1 + zrow*ldw1 + kt*32 + (o&3)*8)
                                 : (W2 + zrow*ldw2 + (size_t)(kt - t1)*32 + (o&3)*8);
      gl_lds16(src, &lds[pp*8192 + p2*4096 + (tid>>6)*512]);
    }
  }
}
// Proj W: [16 rows][32 slots][8]; slot s of row holds octet o = s ^ (row&7)
__device__ __forceinline__ void stage_wp(u16* lds, const u16* W8, int nn, int tid){
  const int row = tid >> 5, sl = tid & 31;
  const int o = sl ^ (row & 7);
  gl_lds16(W8 + (size_t)(nn*16 + row)*H + o*8, &lds[L_WP + (tid>>6)*512]);
}

__device__ __forceinline__ void unpk(const u64 (&ra)[4], bf16x8& ah, bf16x8& al){
  u32 hi[4], lo[4];
  #pragma unroll
  for (int i = 0; i < 4; ++i){
    const u32 e0 = (u32)ra[i], e1 = (u32)(ra[i] >> 32);
    hi[i] = (e0 >> 16) | (e1 & 0xffff0000u);
    lo[i] = (e0 & 0xffffu) | (e1 << 16);
  }
  ah = *(bf16x8*)hi; al = *(bf16x8*)lo;
}
__device__ __forceinline__ void unpkf(const u64 (&ra)[4], bf16x8& ah, bf16x8& al){
  u32 hi[4], lo[4];
  #pragma unroll
  for (int i = 0; i < 4; ++i){
    const float f0 = __uint_as_float((u32)ra[i]);
    const float f1 = __uint_as_float((u32)(ra[i] >> 32));
    const u16 h0 = f2bf(f0), h1 = f2bf(f1);
    const u16 l0 = f2bf(f0 - bf2f(h0)), l1 = f2bf(f1 - bf2f(h1));
    hi[i] = (u32)h0 | ((u32)h1 << 16);
    lo[i] = (u32)l0 | ((u32)l1 << 16);
  }
  ah = *(bf16x8*)hi; al = *(bf16x8*)lo;
}

// 8 waves = 4 m-groups x 2 n-halves. MF=2: 128 rows; MF=1: 64 rows; 128 z-cols.
// W fully LDS-resident; A loaded to registers (ald64, 4-buffer pipeline);
// NO intra-phase barriers.
template<int MF, int N1, int NT>
__device__ __forceinline__ void run_layer(u16* lds, const Ph& J,
    const int tid, const int w, const int lr, const int lc, const int nn,
    float (&cst)[MF][4])
{
  const int nh = w & 1, mg = w >> 1;

  int woff[4];
  #pragma unroll
  for (int q = 0; q < 4; ++q){
    const int zr = q*32 + nh*16 + lr;
    woff[q] = zr*64 + ((lc ^ (zr & 7))*8);
  }
  size_t arow[MF];
  #pragma unroll
  for (int mf = 0; mf < MF; ++mf)
    arow[mf] = (J.gb + (size_t)mg*(16*MF) + mf*16 + lr) * H;

  f32x4 acc[MF][4];
  f32x4 accp[MF];
  #pragma unroll
  for (int mf=0; mf<MF; ++mf){
    accp[mf] = (f32x4){0.f,0.f,0.f,0.f};
    #pragma unroll
    for (int q=0; q<4; ++q) acc[mf][q] = (f32x4){0.f,0.f,0.f,0.f};
  }

  auto loadA = [&](int tile, u64 (&ra)[MF][4]){
    if (J.xf && tile < N1){
      #pragma unroll
      for (int mf = 0; mf < MF; ++mf){
        const float* s = J.xf +
            ((J.gb + (size_t)mg*(16*MF) + mf*16 + lr)*S + J.t)*D + tile*32 + lc*8;
        #pragma unroll
        for (int i = 0; i < 4; ++i) ra[mf][i] = *(const u64*)(s + 2*i);
      }
    } else {
      const u32* pln; int k0;
      if (tile < N1){ pln = J.A1; k0 = tile*32; }
      else          { pln = J.A2; k0 = (tile - N1)*32; }
      #pragma unroll
      for (int mf = 0; mf < MF; ++mf){
        const u32* s = pln + arow[mf] + k0 + lc*8;
        #pragma unroll
        for (int i = 0; i < 4; ++i) ra[mf][i] = ald64(s + 2*i);
      }
    }
  };

  auto comp = [&](int tl, u64 (&ra)[MF][4]){
    bf16x8 ah[MF], al[MF];
    const bool xp = (J.xf != nullptr) && (tl < N1);
    #pragma unroll
    for (int mf = 0; mf < MF; ++mf){
      if (xp) unpkf(ra[mf], ah[mf], al[mf]);
      else    unpk (ra[mf], ah[mf], al[mf]);
    }
    const int wb = (tl >> 1) * 8192;
    const int hx = (tl & 1) * 32;
    #pragma unroll
    for (int q = 0; q < 4; ++q){
      const bf16x8 wq = *(const bf16x8*)&lds[wb + (woff[q] ^ hx)];
      #pragma unroll
      for (int mf = 0; mf < MF; ++mf){
        acc[mf][q] = __builtin_amdgcn_mfma_f32_16x16x32_bf16(ah[mf], wq, acc[mf][q], 0,0,0);
        acc[mf][q] = __builtin_amdgcn_mfma_f32_16x16x32_bf16(al[mf], wq, acc[mf][q], 0,0,0);
      }
    }
    if (J.doprj && nh == 0 && tl < 8){
      const int ps = L_WP + lr*256 + (((tl*4 + lc) ^ (lr & 7))*8);
      const bf16x8 wp = *(const bf16x8*)&lds[ps];
      #pragma unroll
      for (int mf = 0; mf < MF; ++mf){
        accp[mf] = __builtin_amdgcn_mfma_f32_16x16x32_bf16(ah[mf], wp, accp[mf], 0,0,0);
        accp[mf] = __builtin_amdgcn_mfma_f32_16x16x32_bf16(al[mf], wp, accp[mf], 0,0,0);
      }
    }
  };

  // 4-deep register pipeline, static buffer names (NT is 12 or 16, both %4==0)
  u64 a0[MF][4], a1[MF][4], a2[MF][4], a3[MF][4];
  loadA(0, a0); loadA(1, a1); loadA(2, a2); loadA(3, a3);
  for (int tl = 0; tl < NT; tl += 4){
    comp(tl + 0, a0); if (tl + 4 < NT) loadA(tl + 4, a0);
    comp(tl + 1, a1); if (tl + 5 < NT) loadA(tl + 5, a1);
    comp(tl + 2, a2); if (tl + 6 < NT) loadA(tl + 6, a2);
    comp(tl + 3, a3); if (tl + 7 < NT) loadA(tl + 7, a3);
  }

  // epilogue: gates -> c,h ; packed coherent h store
  {
    const int j = nn*32 + nh*16 + lr;
    const float b0 = J.bs[j], b1 = J.bs[H+j], b2 = J.bs[2*H+j], b3 = J.bs[3*H+j];
    #pragma unroll
    for (int mf = 0; mf < MF; ++mf){
      #pragma unroll
      for (int r = 0; r < 4; ++r){
        const size_t m = J.gb + (size_t)mg*(16*MF) + mf*16 + lc*4 + r;
        const float ig = fsig (acc[mf][0][r] + b0);
        const float fg = fsig (acc[mf][1][r] + b1);
        const float gg = ftanh(acc[mf][2][r] + b2);
        const float og = fsig (acc[mf][3][r] + b3);
        const float c  = fg*cst[mf][r] + ig*gg;
        cst[mf][r] = c;
        const float h = og * ftanh(c);
        const u16 hb = f2bf(h);
        const u16 lb = f2bf(h - bf2f(hb));
        ast32(J.outP + m*H + j, ((u32)hb << 16) | lb);
      }
    }
    if (J.doprj && nh == 0){
      const int col = nn*16 + lr;
      const float bo = J.bout[col];
      #pragma unroll
      for (int mf = 0; mf < MF; ++mf){
        #pragma unroll
        for (int r = 0; r < 4; ++r){
          const size_t m = J.gb + (size_t)mg*(16*MF) + mf*16 + lc*4 + r;
          J.out[(m*S + J.tau)*D + col] = accp[mf][r] + bo;
        }
      }
    }
  }
}

struct GG {
  const float* x;
  const u16* W[9];
  const float* bs; const float* bout;
  u32* P;           // 9 packed planes of B*H u32 (8 live + 1 sink)
  float* out; u32* flags;
};

// planes: 0,1: eh1  2,3: eh2  4,5: dh1  6,7: dh2  8: sink   (h(t) -> parity (t+1)&1)
__global__ __launch_bounds__(512, 1) void persist(GG g)
{
  __shared__ u16 lds[L_TOT];
  const int tid = threadIdx.x, w = tid>>6, l = tid&63, lr = l&15, lc = l>>4;
  const int bid = blockIdx.x;
  // slice co-located on one XCD (bid%8 == slice%8) — r6-proven decode
  const int slice = bid & 15, idx = bid >> 4, role = idx >> 3, nn = idx & 7;
  const size_t gb0 = (size_t)slice * 128;
  u32* flg = g.flags + slice*16;
  auto P = [&](int i){ return g.P + (size_t)i * PH; };

  // resident W for encoder section + proj W (role0)
  if (role == 0){
    stage_res(lds, nn, tid, g.W[0], D, 4, g.W[1], H, 8);
    stage_wp(lds, g.W[8], nn, tid);
  } else {
    stage_res(lds, nn, tid, g.W[2], H, 8, g.W[3], H, 8);
  }
  asm volatile("s_waitcnt vmcnt(0)" ::: "memory");
  __syncthreads();

  float cE[2][4]  = {{0,0,0,0},{0,0,0,0}};
  float cD0[1][4] = {{0,0,0,0}};
  float cD1[1][4] = {{0,0,0,0}};

  for (int p = 0; p < 388; ++p){
    if (role == 0){
      if (p < 128){
        const int t = p, pr = t&1, pw = (t+1)&1;
        Ph J{g.x, t, nullptr, P(0+pr),
             gb0, g.bs, P(0+pw), 0, nullptr, nullptr, 0};
        run_layer<2,4,12>(lds, J, tid, w, lr, lc, nn, cE);
      } else if (p == 128){
        // switch resident W to decoder L0 (otherwise-idle phase)
        stage_res(lds, nn, tid, g.W[4], H, 8, g.W[5], H, 8);
        asm volatile("s_waitcnt vmcnt(0)" ::: "memory");
        __syncthreads();
      } else if (p >= 129 && p <= 384){
        const int q = p-129, t = q>>1, h = q&1, pr = t&1, pw = (t+1)&1;
        const u32* a1 = (t == 0) ? P(2) : P(6+pr);
        Ph J{nullptr, 0, a1, P(4+pr),
             gb0 + (size_t)h*64, g.bs + 2048, P(4+pw),
             (t >= 1) ? 1 : 0, g.bout, g.out, t-1};
        if (h == 0) run_layer<1,8,16>(lds, J, tid, w, lr, lc, nn, cD0);
        else        run_layer<1,8,16>(lds, J, tid, w, lr, lc, nn, cD1);
      } else if (p >= 386){
        // tail proj(tau=127) for half h: junk LSTM into sink plane
        const int h = p - 386;
        Ph J{nullptr, 0, P(6), P(4),
             gb0 + (size_t)h*64, g.bs + 2048, P(8), 1, g.bout, g.out, 127};
        float cj[1][4] = {{0,0,0,0}};
        run_layer<1,8,16>(lds, J, tid, w, lr, lc, nn, cj);
      }
      // p==385 idle
    } else {
      if (p >= 1 && p <= 128){
        const int t = p-1, pr = t&1, pw = (t+1)&1;
        Ph J{nullptr, 0, P(0+pw), P(2+pr),
             gb0, g.bs + 1024, P(2+pw), 0, nullptr, nullptr, 0};
        run_layer<2,8,16>(lds, J, tid, w, lr, lc, nn, cE);
      } else if (p == 129){
        stage_res(lds, nn, tid, g.W[6], H, 8, g.W[7], H, 8);
        asm volatile("s_waitcnt vmcnt(0)" ::: "memory");
        __syncthreads();
      } else if (p >= 130 && p <= 385){
        const int r2 = p-130, t = r2>>1, h = r2&1, pr = t&1, pw = (t+1)&1;
        Ph J{nullptr, 0, P(4+pw), P(6+pr),
             gb0 + (size_t)h*64, g.bs + 3072, P(6+pw), 0, nullptr, nullptr, 0};
        if (h == 0) run_layer<1,8,16>(lds, J, tid, w, lr, lc, nn, cD0);
        else        run_layer<1,8,16>(lds, J, tid, w, lr, lc, nn, cD1);
      }
    }
    // slice barrier: store-only arrival + parallel flag poll (no RMW, no fences)
    asm volatile("s_waitcnt vmcnt(0)" ::: "memory");
    __syncthreads();
    if (tid == 0) ast32(&flg[idx], (u32)(p + 1));
    if (tid < 16){
      while (ald32(&flg[tid]) < (u32)(p + 1))
        __builtin_amdgcn_s_sleep(1);
    }
    __syncthreads();
  }
}

extern "C" void kernel_launch(void* const* d_in, const int* in_sizes, int n_in,
                              void* d_out, int out_size, void* d_ws, size_t ws_size,
                              hipStream_t stream)
{
  const float* x     = (const float*)d_in[0];
  const float* eWih0 = (const float*)d_in[1];
  const float* eWhh0 = (const float*)d_in[2];
  const float* ebih0 = (const float*)d_in[3];
  const float* ebhh0 = (const float*)d_in[4];
  const float* eWih1 = (const float*)d_in[5];
  const float* eWhh1 = (const float*)d_in[6];
  const float* ebih1 = (const float*)d_in[7];
  const float* ebhh1 = (const float*)d_in[8];
  const float* dWih0 = (const float*)d_in[9];
  const float* dWhh0 = (const float*)d_in[10];
  const float* dbih0 = (const float*)d_in[11];
  const float* dbhh0 = (const float*)d_in[12];
  const float* dWih1 = (const float*)d_in[13];
  const float* dWhh1 = (const float*)d_in[14];
  const float* dbih1 = (const float*)d_in[15];
  const float* dbhh1 = (const float*)d_in[16];
  const float* Wout  = (const float*)d_in[17];
  const float* bout  = (const float*)d_in[18];
  float* out = (float*)d_out;

  // ---- workspace layout ----
  u16* wc = (u16*)d_ws;
  const int szW[9] = {4*H*D, 4*H*H, 4*H*H, 4*H*H, 4*H*H, 4*H*H, 4*H*H, 4*H*H, D*H};
  const float* srcW[9] = {eWih0,eWhh0,eWih1,eWhh1,dWih0,dWhh0,dWih1,dWhh1,Wout};
  u16* dstW[9]; size_t woff = 0;
  for (int i = 0; i < 9; ++i){ dstW[i] = wc + woff; woff += (size_t)szW[i]; }
  woff = (woff + 7) & ~(size_t)7;
  float* bs = (float*)(wc + woff);
  u32* pl    = (u32*)(bs + 4*1024);      // planes P0..P8 (9*PH u32), then flags
  u32* flags = pl + 9*PH;                // 16 slices x 16 u32

  for (int i = 0; i < 9; ++i)
    cvtk<<<dim3((szW[i]+1023)/1024), dim3(256), 0, stream>>>(srcW[i], dstW[i], szW[i]);
  addk<<<dim3(4), dim3(256), 0, stream>>>(ebih0, ebhh0, bs,        1024);
  addk<<<dim3(4), dim3(256), 0, stream>>>(ebih1, ebhh1, bs + 1024, 1024);
  addk<<<dim3(4), dim3(256), 0, stream>>>(dbih0, dbhh0, bs + 2048, 1024);
  addk<<<dim3(4), dim3(256), 0, stream>>>(dbih1, dbhh1, bs + 3072, 1024);
  // zero ALL planes AND flags every call (graph replays included)
  hipMemsetAsync(pl, 0, (9*PH + 1024) * sizeof(u32), stream);

  GG g;
  g.x = x;
  for (int i = 0; i < 9; ++i) g.W[i] = dstW[i];
  g.bs = bs; g.bout = bout;
  g.P = pl; g.out = out; g.flags = flags;

  persist<<<dim3(256), dim3(512), 0, stream>>>(g);
}

// Round 12
// 6311.490 us; speedup vs baseline: 1.4217x; 1.4217x over previous
//
#include <hip/hip_runtime.h>

typedef short bf16x8 __attribute__((ext_vector_type(8)));
typedef float f32x4 __attribute__((ext_vector_type(4)));
typedef unsigned short u16;
typedef unsigned int u32;
typedef unsigned long long u64;

static constexpr int B = 2048, S = 128, D = 128, H = 256;
static constexpr size_t PH = (size_t)B * H;

// LDS (u16 units): WRES up to 8 pair-tiles x [128 zr][64 k] = 65536 (128KB)
//                  WP  [16 rows][32 slots][8]               = 4096  (8KB)
#define L_WP   65536
#define L_TOT  69632     // 139264 bytes

__device__ __forceinline__ u16 f2bf(float x){ u32 u=__float_as_uint(x); return (u16)((u + 0x7fffu + ((u>>16)&1u))>>16); }
__device__ __forceinline__ float bf2f(u16 h){ return __uint_as_float(((u32)h)<<16); }
__device__ __forceinline__ float fsig(float x){ return 1.0f/(1.0f+__expf(-x)); }
__device__ __forceinline__ float ftanh(float x){ return 1.0f - 2.0f/(__expf(2.0f*x)+1.0f); }

__device__ __forceinline__ void gl_lds16(const void* g, const u16* l){
  __builtin_amdgcn_global_load_lds((const __attribute__((address_space(1))) void*)g,
      (__attribute__((address_space(3))) void*)l, 16, 0, 0);
}
__device__ __forceinline__ u64 ald64(const u32* p){
  return __hip_atomic_load((const u64*)p, __ATOMIC_RELAXED, __HIP_MEMORY_SCOPE_AGENT);
}
__device__ __forceinline__ u32 ald32(const u32* p){
  return __hip_atomic_load(p, __ATOMIC_RELAXED, __HIP_MEMORY_SCOPE_AGENT);
}
__device__ __forceinline__ void ast32(u32* p, u32 v){
  __hip_atomic_store(p, v, __ATOMIC_RELAXED, __HIP_MEMORY_SCOPE_AGENT);
}

__global__ __launch_bounds__(256) void cvtk(const float* __restrict__ s, u16* __restrict__ d, int n){
  int i = (blockIdx.x*256 + threadIdx.x)*4;
  if (i+3 < n){
    float4 v = *(const float4*)(s+i);
    d[i]=f2bf(v.x); d[i+1]=f2bf(v.y); d[i+2]=f2bf(v.z); d[i+3]=f2bf(v.w);
  }
}
__global__ __launch_bounds__(256) void addk(const float* __restrict__ a, const float* __restrict__ b,
                                            float* __restrict__ o, int n){
  int i = blockIdx.x*256 + threadIdx.x; if (i<n) o[i]=a[i]+b[i];
}

struct Ph {
  const float* xf; int t;          // fp32 x source for tiles < N1 (enc L0) or null
  const u32 *A1, *A2;              // packed hi|lo u32 planes, FRAGMENT-BLOCKED layout
  size_t gb;                       // batch-row base (block covers 64*MF rows)
  const float* bs;                 // fused bias (4H fp32)
  u32* outP;                       // h output plane (packed hi|lo, fragment-blocked)
  int doprj; const float* bout; float* out; int tau;
};

// Plane layout (fragment-blocked): element (m, j) lives at
//   ((m>>4)*(H/8) + (j>>3))*128 + (m&15)*8 + (j&7)
// so an MFMA A-fragment lane (row=m&15, 8 consecutive j) reads 8 CONTIGUOUS u32.

// Resident W: pair-tiles [128 zr][64 k]; slot s holds k-octet o = s ^ (zr&7)
// (o>>2 selects K32 tile within pair, o&3 octet). Linear LDS dest,
// swizzle applied on the global source address.
__device__ __forceinline__ void stage_res(u16* lds, int nn, int tid,
    const u16* W1, int ldw1, int t1, const u16* W2, int ldw2, int t2){
  const int np = (t1 + t2) >> 1;
  for (int pp = 0; pp < np; ++pp){
    #pragma unroll
    for (int p2 = 0; p2 < 2; ++p2){
      const int idx = p2*512 + tid;
      const int zr = idx >> 3, sl = idx & 7;
      const int o = sl ^ (zr & 7);
      const int kt = pp*2 + (o >> 2);
      const size_t zrow = (size_t)((zr >> 5) * H + nn*32 + (zr & 31));
      const u16* src = (kt < t1) ? (W1 + zrow*ldw1 + kt*32 + (o&3)*8)
                                 : (W2 + zrow*ldw2 + (size_t)(kt - t1)*32 + (o&3)*8);
      gl_lds16(src, &lds[pp*8192 + p2*4096 + (tid>>6)*512]);
    }
  }
}
// Proj W: [16 rows][32 slots][8]; slot s of row holds octet o = s ^ (row&7)
__device__ __forceinline__ void stage_wp(u16* lds, const u16* W8, int nn, int tid){
  const int row = tid >> 5, sl = tid & 31;
  const int o = sl ^ (row & 7);
  gl_lds16(W8 + (size_t)(nn*16 + row)*H + o*8, &lds[L_WP + (tid>>6)*512]);
}

__device__ __forceinline__ void unpk(const u64 (&ra)[4], bf16x8& ah, bf16x8& al){
  u32 hi[4], lo[4];
  #pragma unroll
  for (int i = 0; i < 4; ++i){
    const u32 e0 = (u32)ra[i], e1 = (u32)(ra[i] >> 32);
    hi[i] = (e0 >> 16) | (e1 & 0xffff0000u);
    lo[i] = (e0 & 0xffffu) | (e1 << 16);
  }
  ah = *(bf16x8*)hi; al = *(bf16x8*)lo;
}
__device__ __forceinline__ void unpkf(const u64 (&ra)[4], bf16x8& ah, bf16x8& al){
  u32 hi[4], lo[4];
  #pragma unroll
  for (int i = 0; i < 4; ++i){
    const float f0 = __uint_as_float((u32)ra[i]);
    const float f1 = __uint_as_float((u32)(ra[i] >> 32));
    const u16 h0 = f2bf(f0), h1 = f2bf(f1);
    const u16 l0 = f2bf(f0 - bf2f(h0)), l1 = f2bf(f1 - bf2f(h1));
    hi[i] = (u32)h0 | ((u32)h1 << 16);
    lo[i] = (u32)l0 | ((u32)l1 << 16);
  }
  ah = *(bf16x8*)hi; al = *(bf16x8*)lo;
}

// 8 waves = 4 m-groups x 2 n-halves. MF=2: 128 rows; MF=1: 64 rows; 128 z-cols.
// W fully LDS-resident; A loaded to registers (ald64, 4-buffer pipeline,
// COALESCED via fragment-blocked plane layout); NO intra-phase barriers.
template<int MF, int N1, int NT>
__device__ __forceinline__ void run_layer(u16* lds, const Ph& J,
    const int tid, const int w, const int lr, const int lc, const int nn,
    float (&cst)[MF][4])
{
  const int nh = w & 1, mg = w >> 1;

  int woff[4];
  #pragma unroll
  for (int q = 0; q < 4; ++q){
    const int zr = q*32 + nh*16 + lr;
    woff[q] = zr*64 + ((lc ^ (zr & 7))*8);
  }
  size_t mrow4[MF];
  #pragma unroll
  for (int mf = 0; mf < MF; ++mf)
    mrow4[mf] = (J.gb + (size_t)mg*(16*MF) + mf*16) >> 4;   // 16-row block index

  f32x4 acc[MF][4];
  f32x4 accp[MF];
  #pragma unroll
  for (int mf=0; mf<MF; ++mf){
    accp[mf] = (f32x4){0.f,0.f,0.f,0.f};
    #pragma unroll
    for (int q=0; q<4; ++q) acc[mf][q] = (f32x4){0.f,0.f,0.f,0.f};
  }

  auto loadA = [&](int tile, u64 (&ra)[MF][4]){
    if (J.xf && tile < N1){
      #pragma unroll
      for (int mf = 0; mf < MF; ++mf){
        const float* s = J.xf +
            ((J.gb + (size_t)mg*(16*MF) + mf*16 + lr)*S + J.t)*D + tile*32 + lc*8;
        #pragma unroll
        for (int i = 0; i < 4; ++i) ra[mf][i] = *(const u64*)(s + 2*i);
      }
    } else {
      const u32* pln; int k0;
      if (tile < N1){ pln = J.A1; k0 = tile*32; }
      else          { pln = J.A2; k0 = (tile - N1)*32; }
      #pragma unroll
      for (int mf = 0; mf < MF; ++mf){
        // fragment-blocked: lane's 8 u32 are contiguous
        const u32* s = pln + ((mrow4[mf]*32 + (size_t)((k0 >> 3) + lc)) << 7) + lr*8;
        #pragma unroll
        for (int i = 0; i < 4; ++i) ra[mf][i] = ald64(s + 2*i);
      }
    }
  };

  auto comp = [&](int tl, u64 (&ra)[MF][4]){
    bf16x8 ah[MF], al[MF];
    const bool xp = (J.xf != nullptr) && (tl < N1);
    #pragma unroll
    for (int mf = 0; mf < MF; ++mf){
      if (xp) unpkf(ra[mf], ah[mf], al[mf]);
      else    unpk (ra[mf], ah[mf], al[mf]);
    }
    const int wb = (tl >> 1) * 8192;
    const int hx = (tl & 1) * 32;
    #pragma unroll
    for (int q = 0; q < 4; ++q){
      const bf16x8 wq = *(const bf16x8*)&lds[wb + (woff[q] ^ hx)];
      #pragma unroll
      for (int mf = 0; mf < MF; ++mf){
        acc[mf][q] = __builtin_amdgcn_mfma_f32_16x16x32_bf16(ah[mf], wq, acc[mf][q], 0,0,0);
        acc[mf][q] = __builtin_amdgcn_mfma_f32_16x16x32_bf16(al[mf], wq, acc[mf][q], 0,0,0);
      }
    }
    if (J.doprj && nh == 0 && tl < 8){
      const int ps = L_WP + lr*256 + (((tl*4 + lc) ^ (lr & 7))*8);
      const bf16x8 wp = *(const bf16x8*)&lds[ps];
      #pragma unroll
      for (int mf = 0; mf < MF; ++mf){
        accp[mf] = __builtin_amdgcn_mfma_f32_16x16x32_bf16(ah[mf], wp, accp[mf], 0,0,0);
        accp[mf] = __builtin_amdgcn_mfma_f32_16x16x32_bf16(al[mf], wp, accp[mf], 0,0,0);
      }
    }
  };

  // 4-deep register pipeline, static buffer names (NT is 12 or 16, both %4==0)
  u64 a0[MF][4], a1[MF][4], a2[MF][4], a3[MF][4];
  loadA(0, a0); loadA(1, a1); loadA(2, a2); loadA(3, a3);
  for (int tl = 0; tl < NT; tl += 4){
    comp(tl + 0, a0); if (tl + 4 < NT) loadA(tl + 4, a0);
    comp(tl + 1, a1); if (tl + 5 < NT) loadA(tl + 5, a1);
    comp(tl + 2, a2); if (tl + 6 < NT) loadA(tl + 6, a2);
    comp(tl + 3, a3); if (tl + 7 < NT) loadA(tl + 7, a3);
  }

  // epilogue: gates -> c,h ; packed coherent h store (fragment-blocked index)
  {
    const int j = nn*32 + nh*16 + lr;
    const int jb = j >> 3, jl = j & 7;
    const float b0 = J.bs[j], b1 = J.bs[H+j], b2 = J.bs[2*H+j], b3 = J.bs[3*H+j];
    #pragma unroll
    for (int mf = 0; mf < MF; ++mf){
      #pragma unroll
      for (int r = 0; r < 4; ++r){
        const float ig = fsig (acc[mf][0][r] + b0);
        const float fg = fsig (acc[mf][1][r] + b1);
        const float gg = ftanh(acc[mf][2][r] + b2);
        const float og = fsig (acc[mf][3][r] + b3);
        const float c  = fg*cst[mf][r] + ig*gg;
        cst[mf][r] = c;
        const float h = og * ftanh(c);
        const u16 hb = f2bf(h);
        const u16 lb = f2bf(h - bf2f(hb));
        const size_t pidx = ((mrow4[mf]*32 + (size_t)jb) << 7) + (lc*4 + r)*8 + jl;
        ast32(J.outP + pidx, ((u32)hb << 16) | lb);
      }
    }
    if (J.doprj && nh == 0){
      const int col = nn*16 + lr;
      const float bo = J.bout[col];
      #pragma unroll
      for (int mf = 0; mf < MF; ++mf){
        #pragma unroll
        for (int r = 0; r < 4; ++r){
          const size_t m = J.gb + (size_t)mg*(16*MF) + mf*16 + lc*4 + r;
          J.out[(m*S + J.tau)*D + col] = accp[mf][r] + bo;
        }
      }
    }
  }
}

struct GG {
  const float* x;
  const u16* W[9];
  const float* bs; const float* bout;
  u32* P;           // 9 packed planes of B*H u32 (8 live + 1 sink)
  float* out; u32* flags;
};

// planes: 0,1: eh1  2,3: eh2  4,5: dh1  6,7: dh2  8: sink   (h(t) -> parity (t+1)&1)
__global__ __launch_bounds__(512, 1) void persist(GG g)
{
  __shared__ u16 lds[L_TOT];
  const int tid = threadIdx.x, w = tid>>6, l = tid&63, lr = l&15, lc = l>>4;
  const int bid = blockIdx.x;
  // slice co-located on one XCD (bid%8 == slice%8) — r6-proven decode
  const int slice = bid & 15, idx = bid >> 4, role = idx >> 3, nn = idx & 7;
  const size_t gb0 = (size_t)slice * 128;
  u32* flg = g.flags + slice*16;
  auto P = [&](int i){ return g.P + (size_t)i * PH; };

  // resident W for encoder section + proj W (role0)
  if (role == 0){
    stage_res(lds, nn, tid, g.W[0], D, 4, g.W[1], H, 8);
    stage_wp(lds, g.W[8], nn, tid);
  } else {
    stage_res(lds, nn, tid, g.W[2], H, 8, g.W[3], H, 8);
  }
  asm volatile("s_waitcnt vmcnt(0)" ::: "memory");
  __syncthreads();

  float cE[2][4]  = {{0,0,0,0},{0,0,0,0}};
  float cD0[1][4] = {{0,0,0,0}};
  float cD1[1][4] = {{0,0,0,0}};

  for (int p = 0; p < 388; ++p){
    if (role == 0){
      if (p < 128){
        const int t = p, pr = t&1, pw = (t+1)&1;
        Ph J{g.x, t, nullptr, P(0+pr),
             gb0, g.bs, P(0+pw), 0, nullptr, nullptr, 0};
        run_layer<2,4,12>(lds, J, tid, w, lr, lc, nn, cE);
      } else if (p == 128){
        // switch resident W to decoder L0 (otherwise-idle phase)
        stage_res(lds, nn, tid, g.W[4], H, 8, g.W[5], H, 8);
        asm volatile("s_waitcnt vmcnt(0)" ::: "memory");
        __syncthreads();
      } else if (p >= 129 && p <= 384){
        const int q = p-129, t = q>>1, h = q&1, pr = t&1, pw = (t+1)&1;
        const u32* a1 = (t == 0) ? P(2) : P(6+pr);
        Ph J{nullptr, 0, a1, P(4+pr),
             gb0 + (size_t)h*64, g.bs + 2048, P(4+pw),
             (t >= 1) ? 1 : 0, g.bout, g.out, t-1};
        if (h == 0) run_layer<1,8,16>(lds, J, tid, w, lr, lc, nn, cD0);
        else        run_layer<1,8,16>(lds, J, tid, w, lr, lc, nn, cD1);
      } else if (p >= 386){
        // tail proj(tau=127) for half h: junk LSTM into sink plane
        const int h = p - 386;
        Ph J{nullptr, 0, P(6), P(4),
             gb0 + (size_t)h*64, g.bs + 2048, P(8), 1, g.bout, g.out, 127};
        float cj[1][4] = {{0,0,0,0}};
        run_layer<1,8,16>(lds, J, tid, w, lr, lc, nn, cj);
      }
      // p==385 idle
    } else {
      if (p >= 1 && p <= 128){
        const int t = p-1, pr = t&1, pw = (t+1)&1;
        Ph J{nullptr, 0, P(0+pw), P(2+pr),
             gb0, g.bs + 1024, P(2+pw), 0, nullptr, nullptr, 0};
        run_layer<2,8,16>(lds, J, tid, w, lr, lc, nn, cE);
      } else if (p == 129){
        stage_res(lds, nn, tid, g.W[6], H, 8, g.W[7], H, 8);
        asm volatile("s_waitcnt vmcnt(0)" ::: "memory");
        __syncthreads();
      } else if (p >= 130 && p <= 385){
        const int r2 = p-130, t = r2>>1, h = r2&1, pr = t&1, pw = (t+1)&1;
        Ph J{nullptr, 0, P(4+pw), P(6+pr),
             gb0 + (size_t)h*64, g.bs + 3072, P(6+pw), 0, nullptr, nullptr, 0};
        if (h == 0) run_layer<1,8,16>(lds, J, tid, w, lr, lc, nn, cD0);
        else        run_layer<1,8,16>(lds, J, tid, w, lr, lc, nn, cD1);
      }
    }
    // slice barrier: store-only arrival + parallel flag poll (no RMW, no fences)
    asm volatile("s_waitcnt vmcnt(0)" ::: "memory");
    __syncthreads();
    if (tid == 0) ast32(&flg[idx], (u32)(p + 1));
    if (tid < 16){
      while (ald32(&flg[tid]) < (u32)(p + 1))
        __builtin_amdgcn_s_sleep(1);
    }
    __syncthreads();
  }
}

extern "C" void kernel_launch(void* const* d_in, const int* in_sizes, int n_in,
                              void* d_out, int out_size, void* d_ws, size_t ws_size,
                              hipStream_t stream)
{
  const float* x     = (const float*)d_in[0];
  const float* eWih0 = (const float*)d_in[1];
  const float* eWhh0 = (const float*)d_in[2];
  const float* ebih0 = (const float*)d_in[3];
  const float* ebhh0 = (const float*)d_in[4];
  const float* eWih1 = (const float*)d_in[5];
  const float* eWhh1 = (const float*)d_in[6];
  const float* ebih1 = (const float*)d_in[7];
  const float* ebhh1 = (const float*)d_in[8];
  const float* dWih0 = (const float*)d_in[9];
  const float* dWhh0 = (const float*)d_in[10];
  const float* dbih0 = (const float*)d_in[11];
  const float* dbhh0 = (const float*)d_in[12];
  const float* dWih1 = (const float*)d_in[13];
  const float* dWhh1 = (const float*)d_in[14];
  const float* dbih1 = (const float*)d_in[15];
  const float* dbhh1 = (const float*)d_in[16];
  const float* Wout  = (const float*)d_in[17];
  const float* bout  = (const float*)d_in[18];
  float* out = (float*)d_out;

  // ---- workspace layout ----
  u16* wc = (u16*)d_ws;
  const int szW[9] = {4*H*D, 4*H*H, 4*H*H, 4*H*H, 4*H*H, 4*H*H, 4*H*H, 4*H*H, D*H};
  const float* srcW[9] = {eWih0,eWhh0,eWih1,eWhh1,dWih0,dWhh0,dWih1,dWhh1,Wout};
  u16* dstW[9]; size_t woff = 0;
  for (int i = 0; i < 9; ++i){ dstW[i] = wc + woff; woff += (size_t)szW[i]; }
  woff = (woff + 7) & ~(size_t)7;
  float* bs = (float*)(wc + woff);
  u32* pl    = (u32*)(bs + 4*1024);      // planes P0..P8 (9*PH u32), then flags
  u32* flags = pl + 9*PH;                // 16 slices x 16 u32

  for (int i = 0; i < 9; ++i)
    cvtk<<<dim3((szW[i]+1023)/1024), dim3(256), 0, stream>>>(srcW[i], dstW[i], szW[i]);
  addk<<<dim3(4), dim3(256), 0, stream>>>(ebih0, ebhh0, bs,        1024);
  addk<<<dim3(4), dim3(256), 0, stream>>>(ebih1, ebhh1, bs + 1024, 1024);
  addk<<<dim3(4), dim3(256), 0, stream>>>(dbih0, dbhh0, bs + 2048, 1024);
  addk<<<dim3(4), dim3(256), 0, stream>>>(dbih1, dbhh1, bs + 3072, 1024);
  // zero ALL planes AND flags every call (graph replays included)
  hipMemsetAsync(pl, 0, (9*PH + 1024) * sizeof(u32), stream);

  GG g;
  g.x = x;
  for (int i = 0; i < 9; ++i) g.W[i] = dstW[i];
  g.bs = bs; g.bout = bout;
  g.P = pl; g.out = out; g.flags = flags;

  persist<<<dim3(256), dim3(512), 0, stream>>>(g);
}

// Round 13
// 4396.061 us; speedup vs baseline: 2.0412x; 1.4357x over previous
//
#include <hip/hip_runtime.h>

typedef short bf16x8 __attribute__((ext_vector_type(8)));
typedef float f32x4 __attribute__((ext_vector_type(4)));
typedef int v4i __attribute__((ext_vector_type(4)));
typedef unsigned int u32x2 __attribute__((ext_vector_type(2)));
typedef unsigned short u16;
typedef unsigned int u32;
typedef unsigned long long u64;

static constexpr int B = 2048, S = 128, D = 128, H = 256;
static constexpr size_t PH = (size_t)B * H;

// LDS (u16 units): WRES up to 8 pair-tiles x [128 zr][64 k] = 65536 (128KB)
//                  WP  [16 rows][32 slots][8]               = 4096  (8KB)
#define L_WP   65536
#define L_TOT  69632     // 139264 bytes

__device__ __forceinline__ u16 f2bf(float x){ u32 u=__float_as_uint(x); return (u16)((u + 0x7fffu + ((u>>16)&1u))>>16); }
__device__ __forceinline__ float bf2f(u16 h){ return __uint_as_float(((u32)h)<<16); }
__device__ __forceinline__ float fsig(float x){ return 1.0f/(1.0f+__expf(-x)); }
__device__ __forceinline__ float ftanh(float x){ return 1.0f - 2.0f/(__expf(2.0f*x)+1.0f); }

__device__ __forceinline__ void gl_lds16(const void* g, const u16* l){
  __builtin_amdgcn_global_load_lds((const __attribute__((address_space(1))) void*)g,
      (__attribute__((address_space(3))) void*)l, 16, 0, 0);
}
__device__ __forceinline__ u64 ald64(const u32* p){
  return __hip_atomic_load((const u64*)p, __ATOMIC_RELAXED, __HIP_MEMORY_SCOPE_AGENT);
}
__device__ __forceinline__ u32 ald32(const u32* p){
  return __hip_atomic_load(p, __ATOMIC_RELAXED, __HIP_MEMORY_SCOPE_AGENT);
}
__device__ __forceinline__ void ast32(u32* p, u32 v){
  __hip_atomic_store(p, v, __ATOMIC_RELAXED, __HIP_MEMORY_SCOPE_AGENT);
}

// CK-style raw buffer load (sc0 = L1-bypass, XCD-L2-served); compiler tracks vmcnt.
__device__ u32x2 bufld2(v4i rsrc, int voffset, int soffset, int aux)
    __asm("llvm.amdgcn.raw.buffer.load.v2i32");
__device__ __forceinline__ v4i mkrsrc(const void* p){
  const u64 a = (u64)p;
  v4i r;
  r.x = (int)(u32)a;
  r.y = (int)(u32)(a >> 32);   // stride=0, addr<2^48
  r.z = -1;                    // num_records: bounds check disabled
  r.w = 0x00020000;            // raw dword access
  return r;
}

__global__ __launch_bounds__(256) void cvtk(const float* __restrict__ s, u16* __restrict__ d, int n){
  int i = (blockIdx.x*256 + threadIdx.x)*4;
  if (i+3 < n){
    float4 v = *(const float4*)(s+i);
    d[i]=f2bf(v.x); d[i+1]=f2bf(v.y); d[i+2]=f2bf(v.z); d[i+3]=f2bf(v.w);
  }
}
__global__ __launch_bounds__(256) void addk(const float* __restrict__ a, const float* __restrict__ b,
                                            float* __restrict__ o, int n){
  int i = blockIdx.x*256 + threadIdx.x; if (i<n) o[i]=a[i]+b[i];
}

struct Ph {
  const float* xf; int t;          // fp32 x source for tiles < N1 (enc L0) or null
  const u32 *A1, *A2;              // packed hi|lo u32 planes, FRAGMENT-BLOCKED layout
  size_t gb;                       // batch-row base (block covers 64*MF rows)
  const float* bs;                 // fused bias (4H fp32)
  u32* outP;                       // h output plane (packed hi|lo, fragment-blocked)
  int doprj; const float* bout; float* out; int tau;
};

// Plane layout (fragment-blocked): element (m, j) lives at
//   ((m>>4)*(H/8) + (j>>3))*128 + (m&15)*8 + (j&7)
// so an MFMA A-fragment lane (row=m&15, 8 consecutive j) reads 8 CONTIGUOUS u32.

// Resident W: pair-tiles [128 zr][64 k]; slot s holds k-octet o = s ^ (zr&7)
// (o>>2 selects K32 tile within pair, o&3 octet). Linear LDS dest,
// swizzle applied on the global source address.
__device__ __forceinline__ void stage_res(u16* lds, int nn, int tid,
    const u16* W1, int ldw1, int t1, const u16* W2, int ldw2, int t2){
  const int np = (t1 + t2) >> 1;
  for (int pp = 0; pp < np; ++pp){
    #pragma unroll
    for (int p2 = 0; p2 < 2; ++p2){
      const int idx = p2*512 + tid;
      const int zr = idx >> 3, sl = idx & 7;
      const int o = sl ^ (zr & 7);
      const int kt = pp*2 + (o >> 2);
      const size_t zrow = (size_t)((zr >> 5) * H + nn*32 + (zr & 31));
      const u16* src = (kt < t1) ? (W1 + zrow*ldw1 + kt*32 + (o&3)*8)
                                 : (W2 + zrow*ldw2 + (size_t)(kt - t1)*32 + (o&3)*8);
      gl_lds16(src, &lds[pp*8192 + p2*4096 + (tid>>6)*512]);
    }
  }
}
// Proj W: [16 rows][32 slots][8]; slot s of row holds octet o = s ^ (row&7)
__device__ __forceinline__ void stage_wp(u16* lds, const u16* W8, int nn, int tid){
  const int row = tid >> 5, sl = tid & 31;
  const int o = sl ^ (row & 7);
  gl_lds16(W8 + (size_t)(nn*16 + row)*H + o*8, &lds[L_WP + (tid>>6)*512]);
}

__device__ __forceinline__ void unpk(const u64 (&ra)[4], bf16x8& ah, bf16x8& al){
  u32 hi[4], lo[4];
  #pragma unroll
  for (int i = 0; i < 4; ++i){
    const u32 e0 = (u32)ra[i], e1 = (u32)(ra[i] >> 32);
    hi[i] = (e0 >> 16) | (e1 & 0xffff0000u);
    lo[i] = (e0 & 0xffffu) | (e1 << 16);
  }
  ah = *(bf16x8*)hi; al = *(bf16x8*)lo;
}
__device__ __forceinline__ void unpkf(const u64 (&ra)[4], bf16x8& ah, bf16x8& al){
  u32 hi[4], lo[4];
  #pragma unroll
  for (int i = 0; i < 4; ++i){
    const float f0 = __uint_as_float((u32)ra[i]);
    const float f1 = __uint_as_float((u32)(ra[i] >> 32));
    const u16 h0 = f2bf(f0), h1 = f2bf(f1);
    const u16 l0 = f2bf(f0 - bf2f(h0)), l1 = f2bf(f1 - bf2f(h1));
    hi[i] = (u32)h0 | ((u32)h1 << 16);
    lo[i] = (u32)l0 | ((u32)l1 << 16);
  }
  ah = *(bf16x8*)hi; al = *(bf16x8*)lo;
}

// 8 waves = 4 m-groups x 2 n-halves. MF=2: 128 rows; MF=1: 64 rows; 128 z-cols.
// W fully LDS-resident; A loaded to registers (4-buffer pipeline, coalesced
// fragment-blocked layout). coh=true: sc0 buffer loads + plain stores (XCD-L2);
// coh=false: agent-scope atomics (r12-proven fallback).
template<int MF, int N1, int NT>
__device__ __forceinline__ void run_layer(u16* lds, const Ph& J,
    const int tid, const int w, const int lr, const int lc, const int nn,
    const bool coh, float (&cst)[MF][4])
{
  const int nh = w & 1, mg = w >> 1;

  int woff[4];
  #pragma unroll
  for (int q = 0; q < 4; ++q){
    const int zr = q*32 + nh*16 + lr;
    woff[q] = zr*64 + ((lc ^ (zr & 7))*8);
  }
  size_t mrow4[MF];
  #pragma unroll
  for (int mf = 0; mf < MF; ++mf)
    mrow4[mf] = (J.gb + (size_t)mg*(16*MF) + mf*16) >> 4;   // 16-row block index

  const v4i rsA1 = mkrsrc(J.A1), rsA2 = mkrsrc(J.A2);

  f32x4 acc[MF][4];
  f32x4 accp[MF];
  #pragma unroll
  for (int mf=0; mf<MF; ++mf){
    accp[mf] = (f32x4){0.f,0.f,0.f,0.f};
    #pragma unroll
    for (int q=0; q<4; ++q) acc[mf][q] = (f32x4){0.f,0.f,0.f,0.f};
  }

  auto loadA = [&](int tile, u64 (&ra)[MF][4]){
    if (J.xf && tile < N1){
      #pragma unroll
      for (int mf = 0; mf < MF; ++mf){
        const float* s = J.xf +
            ((J.gb + (size_t)mg*(16*MF) + mf*16 + lr)*S + J.t)*D + tile*32 + lc*8;
        #pragma unroll
        for (int i = 0; i < 4; ++i) ra[mf][i] = *(const u64*)(s + 2*i);
      }
    } else {
      const int k0 = (tile < N1) ? tile*32 : (tile - N1)*32;
      #pragma unroll
      for (int mf = 0; mf < MF; ++mf){
        // fragment-blocked: lane's 8 u32 are contiguous
        const size_t eoff = ((mrow4[mf]*32 + (size_t)((k0 >> 3) + lc)) << 7) + (size_t)lr*8;
        if (coh){
          const v4i rs = (tile < N1) ? rsA1 : rsA2;
          const int boff = (int)(eoff * 4u);
          #pragma unroll
          for (int i = 0; i < 4; ++i){
            u32x2 v = bufld2(rs, boff + 8*i, 0, 1);   // aux=1 -> sc0 (L2-served)
            ra[mf][i] = (u64)v.x | ((u64)v.y << 32);
          }
        } else {
          const u32* s = ((tile < N1) ? J.A1 : J.A2) + eoff;
          #pragma unroll
          for (int i = 0; i < 4; ++i) ra[mf][i] = ald64(s + 2*i);
        }
      }
    }
  };

  auto comp = [&](int tl, u64 (&ra)[MF][4]){
    bf16x8 ah[MF], al[MF];
    const bool xp = (J.xf != nullptr) && (tl < N1);
    #pragma unroll
    for (int mf = 0; mf < MF; ++mf){
      if (xp) unpkf(ra[mf], ah[mf], al[mf]);
      else    unpk (ra[mf], ah[mf], al[mf]);
    }
    const int wb = (tl >> 1) * 8192;
    const int hx = (tl & 1) * 32;
    #pragma unroll
    for (int q = 0; q < 4; ++q){
      const bf16x8 wq = *(const bf16x8*)&lds[wb + (woff[q] ^ hx)];
      #pragma unroll
      for (int mf = 0; mf < MF; ++mf){
        acc[mf][q] = __builtin_amdgcn_mfma_f32_16x16x32_bf16(ah[mf], wq, acc[mf][q], 0,0,0);
        acc[mf][q] = __builtin_amdgcn_mfma_f32_16x16x32_bf16(al[mf], wq, acc[mf][q], 0,0,0);
      }
    }
    if (J.doprj && nh == 0 && tl < 8){
      const int ps = L_WP + lr*256 + (((tl*4 + lc) ^ (lr & 7))*8);
      const bf16x8 wp = *(const bf16x8*)&lds[ps];
      #pragma unroll
      for (int mf = 0; mf < MF; ++mf){
        accp[mf] = __builtin_amdgcn_mfma_f32_16x16x32_bf16(ah[mf], wp, accp[mf], 0,0,0);
        accp[mf] = __builtin_amdgcn_mfma_f32_16x16x32_bf16(al[mf], wp, accp[mf], 0,0,0);
      }
    }
  };

  // 4-deep register pipeline, static buffer names (NT is 12 or 16, both %4==0)
  u64 a0[MF][4], a1[MF][4], a2[MF][4], a3[MF][4];
  loadA(0, a0); loadA(1, a1); loadA(2, a2); loadA(3, a3);
  for (int tl = 0; tl < NT; tl += 4){
    comp(tl + 0, a0); if (tl + 4 < NT) loadA(tl + 4, a0);
    comp(tl + 1, a1); if (tl + 5 < NT) loadA(tl + 5, a1);
    comp(tl + 2, a2); if (tl + 6 < NT) loadA(tl + 6, a2);
    comp(tl + 3, a3); if (tl + 7 < NT) loadA(tl + 7, a3);
  }

  // epilogue: gates -> c,h ; packed h store (fragment-blocked index)
  {
    const int j = nn*32 + nh*16 + lr;
    const int jb = j >> 3, jl = j & 7;
    const float b0 = J.bs[j], b1 = J.bs[H+j], b2 = J.bs[2*H+j], b3 = J.bs[3*H+j];
    #pragma unroll
    for (int mf = 0; mf < MF; ++mf){
      #pragma unroll
      for (int r = 0; r < 4; ++r){
        const float ig = fsig (acc[mf][0][r] + b0);
        const float fg = fsig (acc[mf][1][r] + b1);
        const float gg = ftanh(acc[mf][2][r] + b2);
        const float og = fsig (acc[mf][3][r] + b3);
        const float c  = fg*cst[mf][r] + ig*gg;
        cst[mf][r] = c;
        const float h = og * ftanh(c);
        const u16 hb = f2bf(h);
        const u16 lb = f2bf(h - bf2f(hb));
        const size_t pidx = ((mrow4[mf]*32 + (size_t)jb) << 7) + (lc*4 + r)*8 + jl;
        const u32 val = ((u32)hb << 16) | lb;
        if (coh) J.outP[pidx] = val;      // plain store -> write-through to XCD L2
        else     ast32(J.outP + pidx, val);
      }
    }
    if (J.doprj && nh == 0){
      const int col = nn*16 + lr;
      const float bo = J.bout[col];
      #pragma unroll
      for (int mf = 0; mf < MF; ++mf){
        #pragma unroll
        for (int r = 0; r < 4; ++r){
          const size_t m = J.gb + (size_t)mg*(16*MF) + mf*16 + lc*4 + r;
          J.out[(m*S + J.tau)*D + col] = accp[mf][r] + bo;
        }
      }
    }
  }
}

struct GG {
  const float* x;
  const u16* W[9];
  const float* bs; const float* bout;
  u32* P;           // 9 packed planes of B*H u32 (8 live + 1 sink)
  float* out; u32* flags;
};

// planes: 0,1: eh1  2,3: eh2  4,5: dh1  6,7: dh2  8: sink   (h(t) -> parity (t+1)&1)
__global__ __launch_bounds__(512, 1) void persist(GG g)
{
  __shared__ u16 lds[L_TOT];
  const int tid = threadIdx.x, w = tid>>6, l = tid&63, lr = l&15, lc = l>>4;
  const int bid = blockIdx.x;
  // slice co-located on one XCD (bid%8 == slice%8) — r6-proven decode
  const int slice = bid & 15, idx = bid >> 4, role = idx >> 3, nn = idx & 7;
  const size_t gb0 = (size_t)slice * 128;
  u32* flg = g.flags + slice*16;
  auto P = [&](int i){ return g.P + (size_t)i * PH; };

  // resident W for encoder section + proj W (role0)
  if (role == 0){
    stage_res(lds, nn, tid, g.W[0], D, 4, g.W[1], H, 8);
    stage_wp(lds, g.W[8], nn, tid);
  } else {
    stage_res(lds, nn, tid, g.W[2], H, 8, g.W[3], H, 8);
  }
  asm volatile("s_waitcnt vmcnt(0)" ::: "memory");
  __syncthreads();

  // One-time XCD co-location check (G16: correctness must not assume placement).
  // All 16 blocks of the slice publish their XCC id; coh = all identical.
  bool coh = false;
  {
    u32 xcc;
    asm volatile("s_getreg_b32 %0, hwreg(HW_REG_XCC_ID)" : "=s"(xcc));
    u32* xs = g.flags + 256 + slice*16;      // within zeroed flags region
    if (tid == 0) ast32(&xs[idx], xcc + 1u);
    __syncthreads();
    u32 v0;
    bool done, uni;
    do {
      done = true; uni = true;
      v0 = ald32(&xs[0]);
      for (int i2 = 1; i2 < 16; ++i2){
        const u32 v = ald32(&xs[i2]);
        if (v == 0u) done = false;
        if (v != v0) uni = false;
      }
      if (v0 == 0u) done = false;
      if (!done) __builtin_amdgcn_s_sleep(1);
    } while (!done);
    coh = uni;
    __syncthreads();
  }

  float cE[2][4]  = {{0,0,0,0},{0,0,0,0}};
  float cD0[1][4] = {{0,0,0,0}};
  float cD1[1][4] = {{0,0,0,0}};

  for (int p = 0; p < 388; ++p){
    if (role == 0){
      if (p < 128){
        const int t = p, pr = t&1, pw = (t+1)&1;
        Ph J{g.x, t, nullptr, P(0+pr),
             gb0, g.bs, P(0+pw), 0, nullptr, nullptr, 0};
        run_layer<2,4,12>(lds, J, tid, w, lr, lc, nn, coh, cE);
      } else if (p == 128){
        // switch resident W to decoder L0 (otherwise-idle phase)
        stage_res(lds, nn, tid, g.W[4], H, 8, g.W[5], H, 8);
        asm volatile("s_waitcnt vmcnt(0)" ::: "memory");
        __syncthreads();
      } else if (p >= 129 && p <= 384){
        const int q = p-129, t = q>>1, h = q&1, pr = t&1, pw = (t+1)&1;
        const u32* a1 = (t == 0) ? P(2) : P(6+pr);
        Ph J{nullptr, 0, a1, P(4+pr),
             gb0 + (size_t)h*64, g.bs + 2048, P(4+pw),
             (t >= 1) ? 1 : 0, g.bout, g.out, t-1};
        if (h == 0) run_layer<1,8,16>(lds, J, tid, w, lr, lc, nn, coh, cD0);
        else        run_layer<1,8,16>(lds, J, tid, w, lr, lc, nn, coh, cD1);
      } else if (p >= 386){
        // tail proj(tau=127) for half h: junk LSTM into sink plane
        const int h = p - 386;
        Ph J{nullptr, 0, P(6), P(4),
             gb0 + (size_t)h*64, g.bs + 2048, P(8), 1, g.bout, g.out, 127};
        float cj[1][4] = {{0,0,0,0}};
        run_layer<1,8,16>(lds, J, tid, w, lr, lc, nn, coh, cj);
      }
      // p==385 idle
    } else {
      if (p >= 1 && p <= 128){
        const int t = p-1, pr = t&1, pw = (t+1)&1;
        Ph J{nullptr, 0, P(0+pw), P(2+pr),
             gb0, g.bs + 1024, P(2+pw), 0, nullptr, nullptr, 0};
        run_layer<2,8,16>(lds, J, tid, w, lr, lc, nn, coh, cE);
      } else if (p == 129){
        stage_res(lds, nn, tid, g.W[6], H, 8, g.W[7], H, 8);
        asm volatile("s_waitcnt vmcnt(0)" ::: "memory");
        __syncthreads();
      } else if (p >= 130 && p <= 385){
        const int r2 = p-130, t = r2>>1, h = r2&1, pr = t&1, pw = (t+1)&1;
        Ph J{nullptr, 0, P(4+pw), P(6+pr),
             gb0 + (size_t)h*64, g.bs + 3072, P(6+pw), 0, nullptr, nullptr, 0};
        if (h == 0) run_layer<1,8,16>(lds, J, tid, w, lr, lc, nn, coh, cD0);
        else        run_layer<1,8,16>(lds, J, tid, w, lr, lc, nn, coh, cD1);
      }
    }
    // slice barrier: store-only arrival + parallel flag poll (no RMW, no fences).
    // vmcnt(0) drains plane stores (to L2 or MALL) before the arrival flag.
    asm volatile("s_waitcnt vmcnt(0)" ::: "memory");
    __syncthreads();
    if (tid == 0) ast32(&flg[idx], (u32)(p + 1));
    if (tid < 16){
      while (ald32(&flg[tid]) < (u32)(p + 1))
        __builtin_amdgcn_s_sleep(1);
    }
    __syncthreads();
  }
}

extern "C" void kernel_launch(void* const* d_in, const int* in_sizes, int n_in,
                              void* d_out, int out_size, void* d_ws, size_t ws_size,
                              hipStream_t stream)
{
  const float* x     = (const float*)d_in[0];
  const float* eWih0 = (const float*)d_in[1];
  const float* eWhh0 = (const float*)d_in[2];
  const float* ebih0 = (const float*)d_in[3];
  const float* ebhh0 = (const float*)d_in[4];
  const float* eWih1 = (const float*)d_in[5];
  const float* eWhh1 = (const float*)d_in[6];
  const float* ebih1 = (const float*)d_in[7];
  const float* ebhh1 = (const float*)d_in[8];
  const float* dWih0 = (const float*)d_in[9];
  const float* dWhh0 = (const float*)d_in[10];
  const float* dbih0 = (const float*)d_in[11];
  const float* dbhh0 = (const float*)d_in[12];
  const float* dWih1 = (const float*)d_in[13];
  const float* dWhh1 = (const float*)d_in[14];
  const float* dbih1 = (const float*)d_in[15];
  const float* dbhh1 = (const float*)d_in[16];
  const float* Wout  = (const float*)d_in[17];
  const float* bout  = (const float*)d_in[18];
  float* out = (float*)d_out;

  // ---- workspace layout ----
  u16* wc = (u16*)d_ws;
  const int szW[9] = {4*H*D, 4*H*H, 4*H*H, 4*H*H, 4*H*H, 4*H*H, 4*H*H, 4*H*H, D*H};
  const float* srcW[9] = {eWih0,eWhh0,eWih1,eWhh1,dWih0,dWhh0,dWih1,dWhh1,Wout};
  u16* dstW[9]; size_t woff = 0;
  for (int i = 0; i < 9; ++i){ dstW[i] = wc + woff; woff += (size_t)szW[i]; }
  woff = (woff + 7) & ~(size_t)7;
  float* bs = (float*)(wc + woff);
  u32* pl    = (u32*)(bs + 4*1024);      // planes P0..P8 (9*PH u32), then flags
  u32* flags = pl + 9*PH;                // 16x16 flags + 16x16 xcc slots (zeroed)

  for (int i = 0; i < 9; ++i)
    cvtk<<<dim3((szW[i]+1023)/1024), dim3(256), 0, stream>>>(srcW[i], dstW[i], szW[i]);
  addk<<<dim3(4), dim3(256), 0, stream>>>(ebih0, ebhh0, bs,        1024);
  addk<<<dim3(4), dim3(256), 0, stream>>>(ebih1, ebhh1, bs + 1024, 1024);
  addk<<<dim3(4), dim3(256), 0, stream>>>(dbih0, dbhh0, bs + 2048, 1024);
  addk<<<dim3(4), dim3(256), 0, stream>>>(dbih1, dbhh1, bs + 3072, 1024);
  // zero ALL planes AND flags/xcc slots every call (graph replays included)
  hipMemsetAsync(pl, 0, (9*PH + 1024) * sizeof(u32), stream);

  GG g;
  g.x = x;
  for (int i = 0; i < 9; ++i) g.W[i] = dstW[i];
  g.bs = bs; g.bout = bout;
  g.P = pl; g.out = out; g.flags = flags;

  persist<<<dim3(256), dim3(512), 0, stream>>>(g);
}